// Round 1
// baseline (672.729 us; speedup 1.0000x reference)
//
#include <hip/hip_runtime.h>

#define NT 32768
#define DM 1024
#define NTOT (NT + 128)          // 32896 = 257 * 128 ; 128-row gap separates experts

typedef __bf16 bf16x8 __attribute__((ext_vector_type(8)));
typedef float f32x4 __attribute__((ext_vector_type(4)));

// async global->LDS, 16B per lane; LDS dest is wave-uniform base + lane*16
#define GLD16(g, l)                                                            \
  __builtin_amdgcn_global_load_lds(                                            \
      (const __attribute__((address_space(1))) void*)(g),                      \
      (__attribute__((address_space(3))) void*)(l), 16, 0, 0)

__device__ __forceinline__ unsigned short f2bf(float f) {
  unsigned u = __float_as_uint(f);
  u += 0x7fffu + ((u >> 16) & 1u);   // RNE
  return (unsigned short)(u >> 16);
}

// ---------------- init: idx = -1, counters = 0 ----------------
__global__ void init_k(int* __restrict__ idx, int* __restrict__ counters) {
  int i = blockIdx.x * blockDim.x + threadIdx.x;
  if (i < NTOT) idx[i] = -1;
  if (i < 2) counters[i] = 0;
}

// ------- weight convert+transpose: Wt[n][k] = bf16(W[k][n]) -------
__global__ void wt_k(const float* __restrict__ W, unsigned short* __restrict__ Wt) {
  __shared__ float tile[32][33];
  int tx = threadIdx.x, ty = threadIdx.y;           // 32 x 8
  int n0 = blockIdx.x * 32, k0 = blockIdx.y * 32;
#pragma unroll
  for (int i = 0; i < 32; i += 8)
    tile[ty + i][tx] = W[(size_t)(k0 + ty + i) * DM + n0 + tx];
  __syncthreads();
#pragma unroll
  for (int i = 0; i < 32; i += 8)
    Wt[(size_t)(n0 + ty + i) * DM + k0 + tx] = f2bf(tile[tx][ty + i]);
}

// ------- partition: route tokens, convert x -> bf16 rows -------
// expert0 fills [0, N0) from front; expert1 fills from NTOT-1 downward.
// One wave per token. Ordering within a partition is irrelevant (per-row GEMM).
__global__ void part_k(const float* __restrict__ x, const int* __restrict__ route,
                       unsigned short* __restrict__ xp, int* __restrict__ idx,
                       int* __restrict__ counters) {
  int wave = threadIdx.x >> 6;
  int lane = threadIdx.x & 63;
  int token = blockIdx.x * 4 + wave;
  int slot = 0;
  if (lane == 0) {
    int r = route[token];
    if (r == 0) slot = atomicAdd(&counters[0], 1);
    else        slot = NTOT - 1 - atomicAdd(&counters[1], 1);
    idx[slot] = token;
  }
  slot = __shfl(slot, 0, 64);
  const float4* src = (const float4*)(x + (size_t)token * DM);
  unsigned short* dst = xp + (size_t)slot * DM;
#pragma unroll
  for (int p = 0; p < 4; ++p) {
    float4 v = src[p * 64 + lane];
    union { unsigned short h[4]; ushort4 u4; } pk;
    pk.h[0] = f2bf(v.x); pk.h[1] = f2bf(v.y);
    pk.h[2] = f2bf(v.z); pk.h[3] = f2bf(v.w);
    *(ushort4*)(dst + (size_t)(p * 64 + lane) * 4) = pk.u4;
  }
}

// ------- grouped GEMM: 128x128 tile, BK=32, 4 waves x (4x4) 16x16x32 MFMA -------
__global__ __launch_bounds__(256) void gemm_k(
    const unsigned short* __restrict__ xp,    // [NTOT][DM] bf16
    const unsigned short* __restrict__ Wt,    // [2][DM][DM] bf16, Wt[n][k]
    const float* __restrict__ b1, const float* __restrict__ b2,
    const int* __restrict__ idx, const int* __restrict__ counters,
    float* __restrict__ out) {
  __shared__ unsigned short As[128 * 32];   // [row][k]
  __shared__ unsigned short Bs[128 * 32];   // [col(n)][k]

  const int t = threadIdx.x;
  const int lane = t & 63, wave = t >> 6;
  const int row0 = blockIdx.y * 128;
  const int col0 = blockIdx.x * 128;
  const int n0 = counters[0];
  const int expert = (row0 < n0) ? 0 : 1;   // 128-gap => tiles never mix experts
  const unsigned short* Wte = Wt + (size_t)expert * DM * DM;
  const float* bias = expert ? b2 : b1;

  const int wr = (wave >> 1) * 64;
  const int wc = (wave & 1) * 64;
  const int lr = lane & 15;
  const int lk = (lane >> 4) * 8;

  f32x4 acc[4][4] = {};

  for (int k0 = 0; k0 < DM; k0 += 32) {
#pragma unroll
    for (int p = 0; p < 2; ++p) {
      int q = p * 256 + t;      // 512 chunks of 16B per 128x32 tile
      int r = q >> 2;
      int c = (q & 3) * 8;
      GLD16(xp  + (size_t)(row0 + r) * DM + k0 + c, As + q * 8);
      GLD16(Wte + (size_t)(col0 + r) * DM + k0 + c, Bs + q * 8);
    }
    __syncthreads();
    bf16x8 af[4], bfr[4];
#pragma unroll
    for (int i = 0; i < 4; ++i)
      af[i] = *(const bf16x8*)&As[(wr + i * 16 + lr) * 32 + lk];
#pragma unroll
    for (int j = 0; j < 4; ++j)
      bfr[j] = *(const bf16x8*)&Bs[(wc + j * 16 + lr) * 32 + lk];
#pragma unroll
    for (int i = 0; i < 4; ++i)
#pragma unroll
      for (int j = 0; j < 4; ++j)
        acc[i][j] = __builtin_amdgcn_mfma_f32_16x16x32_bf16(af[i], bfr[j], acc[i][j], 0, 0, 0);
    __syncthreads();
  }

  // epilogue: scatter rows back to original token positions, add bias (fp32)
#pragma unroll
  for (int i = 0; i < 4; ++i) {
#pragma unroll
    for (int reg = 0; reg < 4; ++reg) {
      int gr = row0 + wr + i * 16 + (lane >> 4) * 4 + reg;
      int dest = idx[gr];
      if (dest >= 0) {
#pragma unroll
        for (int j = 0; j < 4; ++j) {
          int gc = col0 + wc + j * 16 + (lane & 15);
          out[(size_t)dest * DM + gc] = acc[i][j][reg] + bias[gc];
        }
      }
    }
  }
}

extern "C" void kernel_launch(void* const* d_in, const int* in_sizes, int n_in,
                              void* d_out, int out_size, void* d_ws, size_t ws_size,
                              hipStream_t stream) {
  const float* x   = (const float*)d_in[0];
  const float* W1  = (const float*)d_in[1];
  const float* b1  = (const float*)d_in[2];
  const float* W2  = (const float*)d_in[3];
  const float* b2  = (const float*)d_in[4];
  const int*   route = (const int*)d_in[5];
  float* out = (float*)d_out;

  char* ws = (char*)d_ws;
  unsigned short* xp = (unsigned short*)ws;                       // NTOT*DM bf16
  size_t off = (size_t)NTOT * DM * 2;
  unsigned short* Wt = (unsigned short*)(ws + off);               // 2*DM*DM bf16
  off += (size_t)2 * DM * DM * 2;
  int* idx = (int*)(ws + off);                                    // NTOT ints
  int* counters = idx + NTOT;                                     // 2 ints

  init_k<<<(NTOT + 255) / 256, 256, 0, stream>>>(idx, counters);
  wt_k<<<dim3(DM / 32, DM / 32), dim3(32, 8), 0, stream>>>(W1, Wt);
  wt_k<<<dim3(DM / 32, DM / 32), dim3(32, 8), 0, stream>>>(W2, Wt + (size_t)DM * DM);
  part_k<<<NT / 4, 256, 0, stream>>>(x, route, xp, idx, counters);
  gemm_k<<<dim3(DM / 128, NTOT / 128), 256, 0, stream>>>(xp, Wt, b1, b2, idx, counters, out);
}

// Round 2
// 365.380 us; speedup vs baseline: 1.8412x; 1.8412x over previous
//
#include <hip/hip_runtime.h>

#define NT 32768
#define DM 1024
#define NTOT (NT + 128)          // 32896 = 257 * 128 ; 128-row gap separates experts

typedef __bf16 bf16x8 __attribute__((ext_vector_type(8)));
typedef float f32x4 __attribute__((ext_vector_type(4)));

// async global->LDS, 16B per lane; LDS dest is wave-uniform base + lane*16
#define GLD16(g, l)                                                            \
  __builtin_amdgcn_global_load_lds(                                            \
      (const __attribute__((address_space(1))) void*)(g),                      \
      (__attribute__((address_space(3))) void*)(l), 16, 0, 0)

__device__ __forceinline__ unsigned short f2bf(float f) {
  unsigned u = __float_as_uint(f);
  u += 0x7fffu + ((u >> 16) & 1u);   // RNE
  return (unsigned short)(u >> 16);
}

// ---------------- init: idx = -1, counters = 0 ----------------
__global__ void init_k(int* __restrict__ idx, int* __restrict__ counters) {
  int i = blockIdx.x * blockDim.x + threadIdx.x;
  if (i < NTOT) idx[i] = -1;
  if (i < 2) counters[i] = 0;
}

// ------- weight convert+transpose: Wt[n][k] = bf16(W[k][n]) -------
__global__ void wt_k(const float* __restrict__ W, unsigned short* __restrict__ Wt) {
  __shared__ float tile[32][33];
  int tx = threadIdx.x, ty = threadIdx.y;           // 32 x 8
  int n0 = blockIdx.x * 32, k0 = blockIdx.y * 32;
#pragma unroll
  for (int i = 0; i < 32; i += 8)
    tile[ty + i][tx] = W[(size_t)(k0 + ty + i) * DM + n0 + tx];
  __syncthreads();
#pragma unroll
  for (int i = 0; i < 32; i += 8)
    Wt[(size_t)(n0 + ty + i) * DM + k0 + tx] = f2bf(tile[tx][ty + i]);
}

// ------- partition: route 64 tokens/block via ballot ranking, copy rows -------
// 2 atomics per BLOCK (not per token): wave 0 ballots its 64 tokens, computes
// intra-wave ranks by prefix-popcount, grabs base offsets for both experts.
// expert0 fills [0, N0) from the front; expert1 fills from NTOT-1 downward.
__global__ __launch_bounds__(256) void part_k(
    const float* __restrict__ x, const int* __restrict__ route,
    unsigned short* __restrict__ xp, int* __restrict__ idx,
    int* __restrict__ counters) {
  __shared__ int slots[64];
  const int t = threadIdx.x, lane = t & 63, wave = t >> 6;
  const int tok0 = blockIdx.x * 64;

  if (wave == 0) {
    int token = tok0 + lane;
    int r = route[token];
    unsigned long long m0 = __ballot(r == 0);
    unsigned long long lt = (1ULL << lane) - 1ULL;
    int rank0 = __popcll(m0 & lt);
    int rank1 = lane - rank0;
    int cnt0 = __popcll(m0);
    int base0 = 0, base1 = 0;
    if (lane == 0) {
      base0 = atomicAdd(&counters[0], cnt0);
      base1 = atomicAdd(&counters[1], 64 - cnt0);
    }
    base0 = __shfl(base0, 0, 64);
    base1 = __shfl(base1, 0, 64);
    int slot = (r == 0) ? (base0 + rank0) : (NTOT - 1 - (base1 + rank1));
    slots[lane] = slot;
    idx[slot] = token;
  }
  __syncthreads();

  // copy 64 rows (fp32 -> bf16), wave w takes rows w, w+4, ...
  for (int row = wave; row < 64; row += 4) {
    const float4* src = (const float4*)(x + (size_t)(tok0 + row) * DM);
    unsigned short* dst = xp + (size_t)slots[row] * DM;
#pragma unroll
    for (int p = 0; p < 4; ++p) {
      float4 v = src[p * 64 + lane];
      union { unsigned short h[4]; ushort4 u4; } pk;
      pk.h[0] = f2bf(v.x); pk.h[1] = f2bf(v.y);
      pk.h[2] = f2bf(v.z); pk.h[3] = f2bf(v.w);
      *(ushort4*)(dst + (size_t)(p * 64 + lane) * 4) = pk.u4;
    }
  }
}

// ------- grouped GEMM: 128x128 tile, BK=32, 4 waves x (4x4) 16x16x32 MFMA -------
__global__ __launch_bounds__(256) void gemm_k(
    const unsigned short* __restrict__ xp,    // [NTOT][DM] bf16
    const unsigned short* __restrict__ Wt,    // [2][DM][DM] bf16, Wt[n][k]
    const float* __restrict__ b1, const float* __restrict__ b2,
    const int* __restrict__ idx, const int* __restrict__ counters,
    float* __restrict__ out) {
  __shared__ unsigned short As[128 * 32];   // [row][k]
  __shared__ unsigned short Bs[128 * 32];   // [col(n)][k]

  const int t = threadIdx.x;
  const int lane = t & 63, wave = t >> 6;
  const int row0 = blockIdx.y * 128;
  const int col0 = blockIdx.x * 128;
  const int n0 = counters[0];
  const int expert = (row0 < n0) ? 0 : 1;   // 128-gap => tiles never mix experts
  const unsigned short* Wte = Wt + (size_t)expert * DM * DM;
  const float* bias = expert ? b2 : b1;

  const int wr = (wave >> 1) * 64;
  const int wc = (wave & 1) * 64;
  const int lr = lane & 15;
  const int lk = (lane >> 4) * 8;

  f32x4 acc[4][4] = {};

  for (int k0 = 0; k0 < DM; k0 += 32) {
#pragma unroll
    for (int p = 0; p < 2; ++p) {
      int q = p * 256 + t;      // 512 chunks of 16B per 128x32 tile
      int r = q >> 2;
      int c = (q & 3) * 8;
      GLD16(xp  + (size_t)(row0 + r) * DM + k0 + c, As + q * 8);
      GLD16(Wte + (size_t)(col0 + r) * DM + k0 + c, Bs + q * 8);
    }
    __syncthreads();
    bf16x8 af[4], bfr[4];
#pragma unroll
    for (int i = 0; i < 4; ++i)
      af[i] = *(const bf16x8*)&As[(wr + i * 16 + lr) * 32 + lk];
#pragma unroll
    for (int j = 0; j < 4; ++j)
      bfr[j] = *(const bf16x8*)&Bs[(wc + j * 16 + lr) * 32 + lk];
#pragma unroll
    for (int i = 0; i < 4; ++i)
#pragma unroll
      for (int j = 0; j < 4; ++j)
        acc[i][j] = __builtin_amdgcn_mfma_f32_16x16x32_bf16(af[i], bfr[j], acc[i][j], 0, 0, 0);
    __syncthreads();
  }

  // epilogue: scatter rows back to original token positions, add bias (fp32)
#pragma unroll
  for (int i = 0; i < 4; ++i) {
#pragma unroll
    for (int reg = 0; reg < 4; ++reg) {
      int gr = row0 + wr + i * 16 + (lane >> 4) * 4 + reg;
      int dest = idx[gr];
      if (dest >= 0) {
#pragma unroll
        for (int j = 0; j < 4; ++j) {
          int gc = col0 + wc + j * 16 + (lane & 15);
          out[(size_t)dest * DM + gc] = acc[i][j][reg] + bias[gc];
        }
      }
    }
  }
}

extern "C" void kernel_launch(void* const* d_in, const int* in_sizes, int n_in,
                              void* d_out, int out_size, void* d_ws, size_t ws_size,
                              hipStream_t stream) {
  const float* x   = (const float*)d_in[0];
  const float* W1  = (const float*)d_in[1];
  const float* b1  = (const float*)d_in[2];
  const float* W2  = (const float*)d_in[3];
  const float* b2  = (const float*)d_in[4];
  const int*   route = (const int*)d_in[5];
  float* out = (float*)d_out;

  char* ws = (char*)d_ws;
  unsigned short* xp = (unsigned short*)ws;                       // NTOT*DM bf16
  size_t off = (size_t)NTOT * DM * 2;
  unsigned short* Wt = (unsigned short*)(ws + off);               // 2*DM*DM bf16
  off += (size_t)2 * DM * DM * 2;
  int* idx = (int*)(ws + off);                                    // NTOT ints
  int* counters = idx + NTOT;                                     // 2 ints

  init_k<<<(NTOT + 255) / 256, 256, 0, stream>>>(idx, counters);
  wt_k<<<dim3(DM / 32, DM / 32), dim3(32, 8), 0, stream>>>(W1, Wt);
  wt_k<<<dim3(DM / 32, DM / 32), dim3(32, 8), 0, stream>>>(W2, Wt + (size_t)DM * DM);
  part_k<<<NT / 64, 256, 0, stream>>>(x, route, xp, idx, counters);
  gemm_k<<<dim3(DM / 128, NTOT / 128), 256, 0, stream>>>(xp, Wt, b1, b2, idx, counters, out);
}

// Round 3
// 358.532 us; speedup vs baseline: 1.8763x; 1.0191x over previous
//
#include <hip/hip_runtime.h>

#define NT 32768
#define DM 1024
#define NTOT (NT + 128)          // 32896 = 257 * 128 ; 128-row gap separates experts

typedef __bf16 bf16x8 __attribute__((ext_vector_type(8)));
typedef float f32x4 __attribute__((ext_vector_type(4)));

// async global->LDS, 16B per lane; LDS dest is wave-uniform base + lane*16
#define GLD16(g, l)                                                            \
  __builtin_amdgcn_global_load_lds(                                            \
      (const __attribute__((address_space(1))) void*)(g),                      \
      (__attribute__((address_space(3))) void*)(l), 16, 0, 0)

__device__ __forceinline__ unsigned short f2bf(float f) {
  unsigned u = __float_as_uint(f);
  u += 0x7fffu + ((u >> 16) & 1u);   // RNE
  return (unsigned short)(u >> 16);
}

// ------- weight convert+transpose: Wt[n][k] = bf16(W[k][n]) -------
__global__ void wt_k(const float* __restrict__ W, unsigned short* __restrict__ Wt) {
  __shared__ float tile[32][33];
  int tx = threadIdx.x, ty = threadIdx.y;           // 32 x 8
  int n0 = blockIdx.x * 32, k0 = blockIdx.y * 32;
#pragma unroll
  for (int i = 0; i < 32; i += 8)
    tile[ty + i][tx] = W[(size_t)(k0 + ty + i) * DM + n0 + tx];
  __syncthreads();
#pragma unroll
  for (int i = 0; i < 32; i += 8)
    Wt[(size_t)(n0 + ty + i) * DM + k0 + tx] = f2bf(tile[tx][ty + i]);
}

// ------- partition: route 64 tokens/block via ballot ranking, copy rows -------
// 2 atomics per BLOCK: wave 0 ballots 64 tokens, prefix-popcount ranks.
// expert0 fills [0, n0) front; expert1 fills from NTOT-1 downward.
// Every slot outside the gap [n0, n0+128) gets written exactly once.
__global__ __launch_bounds__(256) void part_k(
    const float* __restrict__ x, const int* __restrict__ route,
    unsigned short* __restrict__ xp, int* __restrict__ idx,
    int* __restrict__ counters) {
  __shared__ int slots[64];
  const int t = threadIdx.x, lane = t & 63, wave = t >> 6;
  const int tok0 = blockIdx.x * 64;

  if (wave == 0) {
    int token = tok0 + lane;
    int r = route[token];
    unsigned long long m0 = __ballot(r == 0);
    unsigned long long lt = (1ULL << lane) - 1ULL;
    int rank0 = __popcll(m0 & lt);
    int rank1 = lane - rank0;
    int cnt0 = __popcll(m0);
    int base0 = 0, base1 = 0;
    if (lane == 0) {
      base0 = atomicAdd(&counters[0], cnt0);
      base1 = atomicAdd(&counters[1], 64 - cnt0);
    }
    base0 = __shfl(base0, 0, 64);
    base1 = __shfl(base1, 0, 64);
    int slot = (r == 0) ? (base0 + rank0) : (NTOT - 1 - (base1 + rank1));
    slots[lane] = slot;
    idx[slot] = token;
  }
  __syncthreads();

  // copy 64 rows (fp32 -> bf16), wave w takes rows w, w+4, ...
  for (int row = wave; row < 64; row += 4) {
    const float4* src = (const float4*)(x + (size_t)(tok0 + row) * DM);
    unsigned short* dst = xp + (size_t)slots[row] * DM;
#pragma unroll
    for (int p = 0; p < 4; ++p) {
      float4 v = src[p * 64 + lane];
      union { unsigned short h[4]; ushort4 u4; } pk;
      pk.h[0] = f2bf(v.x); pk.h[1] = f2bf(v.y);
      pk.h[2] = f2bf(v.z); pk.h[3] = f2bf(v.w);
      *(ushort4*)(dst + (size_t)(p * 64 + lane) * 4) = pk.u4;
    }
  }
}

// ------- grouped GEMM: 128x128 tile, BK=64, 4 waves x (4x4) 16x16x32 MFMA -------
// LDS XOR-swizzle: global 16B-chunk c of row r lives at LDS chunk r*8 + (c^(r&7)).
// Staging stays lane-contiguous (required by global_load_lds); fragment reads
// spread 16 consecutive rows over all 8 bank-chunk groups -> 2-way (free).
__global__ __launch_bounds__(256, 4) void gemm_k(
    const unsigned short* __restrict__ xp,    // [NTOT][DM] bf16
    const unsigned short* __restrict__ Wt,    // [2][DM][DM] bf16, Wt[n][k]
    const float* __restrict__ b1, const float* __restrict__ b2,
    const int* __restrict__ idx, const int* __restrict__ counters,
    float* __restrict__ out) {
  __shared__ unsigned short As[128 * 64];   // swizzled [row][k-chunk]
  __shared__ unsigned short Bs[128 * 64];

  const int t = threadIdx.x;
  const int lane = t & 63, wave = t >> 6;
  const int row0 = blockIdx.y * 128;
  const int col0 = blockIdx.x * 128;
  const int n0 = counters[0];
  const int expert = (row0 < n0) ? 0 : 1;   // 128-gap => tiles never mix experts
  const unsigned short* Wte = Wt + (size_t)expert * DM * DM;
  const float* bias = expert ? b2 : b1;

  const int wr = (wave >> 1) * 64;
  const int wc = (wave & 1) * 64;
  const int lr = lane & 15;

  f32x4 acc[4][4] = {};

  for (int k0 = 0; k0 < DM; k0 += 64) {
#pragma unroll
    for (int p = 0; p < 4; ++p) {
      int q = p * 256 + t;          // 1024 chunks of 16B per 128x64 tile
      int r = q >> 3;
      int c = ((q & 7) ^ (r & 7)) * 8;   // swizzled global element offset
      GLD16(xp  + (size_t)(row0 + r) * DM + k0 + c, As + q * 8);
      GLD16(Wte + (size_t)(col0 + r) * DM + k0 + c, Bs + q * 8);
    }
    __syncthreads();
#pragma unroll
    for (int s = 0; s < 2; ++s) {
      const int cb = s * 4 + (lane >> 4);   // wanted 16B chunk within the row
      bf16x8 af[4], bfr[4];
#pragma unroll
      for (int i = 0; i < 4; ++i) {
        int r = wr + i * 16 + lr;
        af[i] = *(const bf16x8*)&As[(r * 8 + (cb ^ (r & 7))) * 8];
      }
#pragma unroll
      for (int j = 0; j < 4; ++j) {
        int r = wc + j * 16 + lr;
        bfr[j] = *(const bf16x8*)&Bs[(r * 8 + (cb ^ (r & 7))) * 8];
      }
#pragma unroll
      for (int i = 0; i < 4; ++i)
#pragma unroll
        for (int j = 0; j < 4; ++j)
          acc[i][j] = __builtin_amdgcn_mfma_f32_16x16x32_bf16(af[i], bfr[j], acc[i][j], 0, 0, 0);
    }
    __syncthreads();
  }

  // epilogue: scatter rows to original token positions, add bias (fp32).
  // gap rows [n0, n0+128) are discarded (their idx/xp were never written).
#pragma unroll
  for (int i = 0; i < 4; ++i) {
#pragma unroll
    for (int reg = 0; reg < 4; ++reg) {
      int gr = row0 + wr + i * 16 + (lane >> 4) * 4 + reg;
      if (gr < n0 || gr >= n0 + 128) {
        int dest = idx[gr];
#pragma unroll
        for (int j = 0; j < 4; ++j) {
          int gc = col0 + wc + j * 16 + (lane & 15);
          out[(size_t)dest * DM + gc] = acc[i][j][reg] + bias[gc];
        }
      }
    }
  }
}

extern "C" void kernel_launch(void* const* d_in, const int* in_sizes, int n_in,
                              void* d_out, int out_size, void* d_ws, size_t ws_size,
                              hipStream_t stream) {
  const float* x   = (const float*)d_in[0];
  const float* W1  = (const float*)d_in[1];
  const float* b1  = (const float*)d_in[2];
  const float* W2  = (const float*)d_in[3];
  const float* b2  = (const float*)d_in[4];
  const int*   route = (const int*)d_in[5];
  float* out = (float*)d_out;

  char* ws = (char*)d_ws;
  unsigned short* xp = (unsigned short*)ws;                       // NTOT*DM bf16
  size_t off = (size_t)NTOT * DM * 2;
  unsigned short* Wt = (unsigned short*)(ws + off);               // 2*DM*DM bf16
  off += (size_t)2 * DM * DM * 2;
  int* idx = (int*)(ws + off);                                    // NTOT ints
  int* counters = idx + NTOT;                                     // 2 ints

  hipMemsetAsync(counters, 0, 2 * sizeof(int), stream);
  part_k<<<NT / 64, 256, 0, stream>>>(x, route, xp, idx, counters);
  wt_k<<<dim3(DM / 32, DM / 32), dim3(32, 8), 0, stream>>>(W1, Wt);
  wt_k<<<dim3(DM / 32, DM / 32), dim3(32, 8), 0, stream>>>(W2, Wt + (size_t)DM * DM);
  gemm_k<<<dim3(DM / 128, NTOT / 128), 256, 0, stream>>>(xp, Wt, b1, b2, idx, counters, out);
}